// Round 2
// baseline (774.936 us; speedup 1.0000x reference)
//
#include <hip/hip_runtime.h>
#include <stdint.h>

// Reference dtypes: sources (B,T,N,D) float32, queries (L,D) float32,
// layer_idx int scalar. Output (B,T,D) float32.
static constexpr int D = 512;
static constexpr int N = 9;
static constexpr float EPS = 1e-6f;

// One wave (64 lanes) per (b,t). Lane owns floats {4*lane..+3} and
// {256+4*lane..+3} of each 512-float row -> every global access is a
// coalesced wave-wide dwordx4 (1024 B per instruction).
__global__ __launch_bounds__(256) void block_attn(
    const float4* __restrict__ src4,
    const float4* __restrict__ q4,
    const int*   __restrict__ layer_idx,
    float4* __restrict__ out4,
    int bt_total)
{
    const int lane = threadIdx.x & 63;
    const int wave = threadIdx.x >> 6;
    const int bt   = blockIdx.x * 4 + wave;
    if (bt >= bt_total) return;

    const int li = layer_idx[0];

    const float4* qp = q4 + (size_t)li * (D / 4);
    const float4 w0 = qp[lane];
    const float4 w1 = qp[64 + lane];

    const float4* p = src4 + (size_t)bt * (N * D / 4) + lane;

    float4 s0[N], s1[N];         // register-resident rows (this lane's slice)
    float score[N];

    #pragma unroll
    for (int n = 0; n < N; ++n) {
        const float4 a = p[(size_t)n * (D / 4)];
        const float4 b = p[(size_t)n * (D / 4) + 64];
        s0[n] = a; s1[n] = b;

        float ss = a.x * a.x;
        ss = fmaf(a.y, a.y, ss); ss = fmaf(a.z, a.z, ss); ss = fmaf(a.w, a.w, ss);
        ss = fmaf(b.x, b.x, ss); ss = fmaf(b.y, b.y, ss);
        ss = fmaf(b.z, b.z, ss); ss = fmaf(b.w, b.w, ss);

        float dt = a.x * w0.x;
        dt = fmaf(a.y, w0.y, dt); dt = fmaf(a.z, w0.z, dt); dt = fmaf(a.w, w0.w, dt);
        dt = fmaf(b.x, w1.x, dt); dt = fmaf(b.y, w1.y, dt);
        dt = fmaf(b.z, w1.z, dt); dt = fmaf(b.w, w1.w, dt);

        // butterfly reduce across the 64-lane wave (all lanes get totals)
        #pragma unroll
        for (int m = 1; m < 64; m <<= 1) {
            ss += __shfl_xor(ss, m, 64);
            dt += __shfl_xor(dt, m, 64);
        }
        // score = dot(s, w) / rms,  rms = sqrt(mean(s^2) + eps)
        score[n] = dt * rsqrtf(ss * (1.0f / 512.0f) + EPS);
    }

    // softmax over N=9 (every lane holds all scores)
    float mx = score[0];
    #pragma unroll
    for (int n = 1; n < N; ++n) mx = fmaxf(mx, score[n]);
    float asum = 0.f;
    float alpha[N];
    #pragma unroll
    for (int n = 0; n < N; ++n) { alpha[n] = __expf(score[n] - mx); asum += alpha[n]; }
    const float inv = 1.0f / asum;

    // h = sum_n alpha_n * sources_n  (raw sources)
    float4 h0 = {0.f, 0.f, 0.f, 0.f};
    float4 h1 = {0.f, 0.f, 0.f, 0.f};
    #pragma unroll
    for (int n = 0; n < N; ++n) {
        const float a = alpha[n] * inv;
        h0.x = fmaf(a, s0[n].x, h0.x); h0.y = fmaf(a, s0[n].y, h0.y);
        h0.z = fmaf(a, s0[n].z, h0.z); h0.w = fmaf(a, s0[n].w, h0.w);
        h1.x = fmaf(a, s1[n].x, h1.x); h1.y = fmaf(a, s1[n].y, h1.y);
        h1.z = fmaf(a, s1[n].z, h1.z); h1.w = fmaf(a, s1[n].w, h1.w);
    }

    float4* op = out4 + (size_t)bt * (D / 4);
    op[lane]      = h0;
    op[64 + lane] = h1;
}

extern "C" void kernel_launch(void* const* d_in, const int* in_sizes, int n_in,
                              void* d_out, int out_size, void* d_ws, size_t ws_size,
                              hipStream_t stream) {
    const float4* src = (const float4*)d_in[0];
    const float4* q   = (const float4*)d_in[1];
    const int*    li  = (const int*)d_in[2];
    float4* out = (float4*)d_out;

    const int bt_total = in_sizes[0] / (N * D);   // B*T = 32768
    const int blocks = (bt_total + 3) / 4;        // 4 waves (one bt each) per block
    block_attn<<<blocks, 256, 0, stream>>>(src, q, li, out, bt_total);
}